// Round 2
// baseline (1673.210 us; speedup 1.0000x reference)
//
#include <hip/hip_runtime.h>
#include <math.h>

#define BB 16
#define NTOK 4096
#define DIM 512
#define HID 2048
#define NGE 4
#define NPE 4
#define NFE 2
#define GIN 4096
#define PIN 1024
#define NCLS 4
#define EPS 1e-5f

// ---- workspace layout (float offsets) ----
#define WS_SUMXN   0            // BB*PIN           = 16384   (zeroed)
#define WS_Z       16384        // NPE*BB*PIN       = 65536   (zeroed)
#define WS_XG      81920        // BB*DIM           = 8192    (zeroed)
#define WS_FG      90112        // 8192                       (zeroed)
#define WS_FP      98304        // 8192                       (zeroed)
#define WS_FIMMF   106496       // 8192                       (zeroed)
#define ACC_TOTAL  114688
#define WS_MEAN    114688       // BB*NTOK = 65536
#define WS_RSTD    180224       // 65536
#define WS_S       245760       // NPE*BB*NTOK = 262144
#define WS_QPROJ   507904       // NPE*PIN = 4096
#define WS_GMEAN   512000       // 16
#define WS_GRSTD   512016       // 16
#define WS_XPMEAN  512032       // 8192
#define WS_POOLED  520224       // NPE*BB*DIM = 32768
#define WS_WG      552992       // 64
#define WS_WP      553056       // 64
#define WS_WF      553120       // 32
#define WS_UG      553152       // 32768
#define WS_UP      585920       // 32768
#define WS_HG      618688       // NGE*BB*HID = 131072
#define WS_HP      749760       // 131072
#define WS_UF      880832       // 16384
#define WS_HF      897216       // NFE*BB*HID = 65536
#define WS_END     962752       // ~3.85 MB

__device__ __forceinline__ float wsum(float v) {
#pragma unroll
    for (int o = 32; o > 0; o >>= 1) v += __shfl_xor(v, o);
    return v;
}
__device__ __forceinline__ float wmax(float v) {
#pragma unroll
    for (int o = 32; o > 0; o >>= 1) v = fmaxf(v, __shfl_xor(v, o));
    return v;
}
__device__ __forceinline__ float gelu_exact(float x) {
    return 0.5f * x * (1.0f + erff(x * 0.70710678118654752f));
}

// ================= K0: zero accumulators, qproj = g .* (path_W @ p_q), gene row stats ===========
__global__ __launch_bounds__(256) void k0_init(const float* __restrict__ F_gene,
                                               const float* __restrict__ path_W,
                                               const float* __restrict__ p_q,
                                               const float* __restrict__ path_ln_g,
                                               float* __restrict__ ws) {
    int blk = blockIdx.x, t = threadIdx.x;
    if (blk < 112) {
        // zero ACC region: 114688 floats = 28672 float4, 112*256 = 28672 threads
        ((float4*)ws)[blk * 256 + t] = make_float4(0.f, 0.f, 0.f, 0.f);
    } else if (blk < 116) {
        __shared__ __align__(16) float pq[NPE * DIM];
        for (int i = t; i < NPE * DIM; i += 256) pq[i] = p_q[i];
        __syncthreads();
        int k = (blk - 112) * 256 + t;           // 0..1023
        const float4* wr = (const float4*)(path_W + (size_t)k * DIM);
        const float4* pq4 = (const float4*)pq;
        float acc[NPE] = {0.f, 0.f, 0.f, 0.f};
        for (int i = 0; i < DIM / 4; i++) {
            float4 w = wr[i];
#pragma unroll
            for (int e = 0; e < NPE; e++) {
                float4 q = pq4[e * (DIM / 4) + i];
                acc[e] += w.x * q.x + w.y * q.y + w.z * q.z + w.w * q.w;
            }
        }
        float g = path_ln_g[k];
#pragma unroll
        for (int e = 0; e < NPE; e++) ws[WS_QPROJ + e * PIN + k] = g * acc[e];
    } else {
        // gene row stats (16 rows of 4096)
        int b = blk - 116;
        const float4* row = (const float4*)(F_gene + (size_t)b * GIN);
        float s1 = 0.f, s2 = 0.f;
        for (int i = t; i < GIN / 4; i += 256) {
            float4 v = row[i];
            s1 += v.x + v.y + v.z + v.w;
            s2 += v.x * v.x + v.y * v.y + v.z * v.z + v.w * v.w;
        }
        __shared__ float sc[8];
        s1 = wsum(s1); s2 = wsum(s2);
        int w = t >> 6;
        if ((t & 63) == 0) { sc[w] = s1; sc[4 + w] = s2; }
        __syncthreads();
        if (t == 0) {
            float S1 = sc[0] + sc[1] + sc[2] + sc[3];
            float S2 = sc[4] + sc[5] + sc[6] + sc[7];
            float m = S1 / GIN;
            float var = S2 / GIN - m * m;
            ws[WS_GMEAN + b] = m;
            ws[WS_GRSTD + b] = rsqrtf(var + EPS);
        }
    }
}

// ================= K1: F_path pass1 — LN stats, score dots, sum of xn =================
// wave per row; lane j-strided float4s cover the FULL 1024-float row.
__global__ __launch_bounds__(256) void k1_pass1(const float* __restrict__ F_path,
                                                float* __restrict__ ws) {
    __shared__ __align__(16) float qlds[NPE * PIN];  // 16 KB
    __shared__ __align__(16) float comb[4 * PIN];    // 16 KB
    int t = threadIdx.x;
    for (int i = t; i < NPE * PIN; i += 256) qlds[i] = ws[WS_QPROJ + i];
    __syncthreads();
    int blk = blockIdx.x;
    int b = blk >> 6, chunk = blk & 63;
    int w = t >> 6, lane = t & 63;
    const float4* qp4 = (const float4*)qlds;
    float4 sxn[4];
#pragma unroll
    for (int j = 0; j < 4; j++) sxn[j] = make_float4(0.f, 0.f, 0.f, 0.f);
    for (int i = 0; i < 16; i++) {
        int n = chunk * 64 + w * 16 + i;
        const float4* rowp = (const float4*)(F_path + ((size_t)(b * NTOK + n)) * PIN);
        float4 x[4];
#pragma unroll
        for (int j = 0; j < 4; j++) x[j] = rowp[lane + 64 * j];
        float s1 = 0.f, s2 = 0.f;
#pragma unroll
        for (int j = 0; j < 4; j++) {
            s1 += x[j].x + x[j].y + x[j].z + x[j].w;
            s2 += x[j].x * x[j].x + x[j].y * x[j].y + x[j].z * x[j].z + x[j].w * x[j].w;
        }
        s1 = wsum(s1); s2 = wsum(s2);
        float m = s1 * (1.f / PIN);
        float var = s2 * (1.f / PIN) - m * m;
        float r = rsqrtf(var + EPS);
        float sc[NPE];
#pragma unroll
        for (int e = 0; e < NPE; e++) {
            float d = 0.f;
#pragma unroll
            for (int j = 0; j < 4; j++) {
                float4 q = qp4[e * (PIN / 4) + lane + 64 * j];
                d += (x[j].x - m) * q.x + (x[j].y - m) * q.y +
                     (x[j].z - m) * q.z + (x[j].w - m) * q.w;
            }
            sc[e] = wsum(d) * r;   // r is wave-uniform
        }
#pragma unroll
        for (int j = 0; j < 4; j++) {
            sxn[j].x += (x[j].x - m) * r;
            sxn[j].y += (x[j].y - m) * r;
            sxn[j].z += (x[j].z - m) * r;
            sxn[j].w += (x[j].w - m) * r;
        }
        if (lane == 0) {
            ws[WS_MEAN + b * NTOK + n] = m;
            ws[WS_RSTD + b * NTOK + n] = r;
#pragma unroll
            for (int e = 0; e < NPE; e++) ws[WS_S + (e * BB + b) * NTOK + n] = sc[e];
        }
    }
    // combine sum_xn across the 4 waves, then one atomic per column per block
    float4* comb4 = (float4*)comb;
#pragma unroll
    for (int j = 0; j < 4; j++) comb4[w * (PIN / 4) + lane + 64 * j] = sxn[j];
    __syncthreads();
    {
        float4 a = comb4[t], bq = comb4[256 + t], c = comb4[512 + t], d = comb4[768 + t];
        float4 tot = make_float4(a.x + bq.x + c.x + d.x, a.y + bq.y + c.y + d.y,
                                 a.z + bq.z + c.z + d.z, a.w + bq.w + c.w + d.w);
        atomicAdd(ws + WS_SUMXN + b * PIN + 4 * t + 0, tot.x);
        atomicAdd(ws + WS_SUMXN + b * PIN + 4 * t + 1, tot.y);
        atomicAdd(ws + WS_SUMXN + b * PIN + 4 * t + 2, tot.z);
        atomicAdd(ws + WS_SUMXN + b * PIN + 4 * t + 3, tot.w);
    }
}

// ================= K2: softmax over n for each (e,b) =================
__global__ __launch_bounds__(256) void k2_softmax(float* __restrict__ ws) {
    int row = blockIdx.x;  // e*BB+b, 64 rows
    float* s = ws + WS_S + (size_t)row * NTOK;
    int t = threadIdx.x, w = t >> 6, lane = t & 63;
    __shared__ float sc[4];
    float4 v[4];
    float mx = -1e30f;
#pragma unroll
    for (int j = 0; j < 4; j++) {
        v[j] = ((float4*)s)[t + j * 256];
        mx = fmaxf(mx, fmaxf(fmaxf(v[j].x, v[j].y), fmaxf(v[j].z, v[j].w)));
    }
    mx = wmax(mx);
    if (lane == 0) sc[w] = mx;
    __syncthreads();
    mx = fmaxf(fmaxf(sc[0], sc[1]), fmaxf(sc[2], sc[3]));
    __syncthreads();
    float sum = 0.f;
#pragma unroll
    for (int j = 0; j < 4; j++) {
        v[j].x = __expf(v[j].x - mx); v[j].y = __expf(v[j].y - mx);
        v[j].z = __expf(v[j].z - mx); v[j].w = __expf(v[j].w - mx);
        sum += v[j].x + v[j].y + v[j].z + v[j].w;
    }
    sum = wsum(sum);
    if (lane == 0) sc[w] = sum;
    __syncthreads();
    float inv = 1.f / (sc[0] + sc[1] + sc[2] + sc[3]);
#pragma unroll
    for (int j = 0; j < 4; j++) {
        v[j].x *= inv; v[j].y *= inv; v[j].z *= inv; v[j].w *= inv;
        ((float4*)s)[t + j * 256] = v[j];
    }
}

// ================= K3: F_path pass2 (z = attn-weighted sum of xn) + gene GEMM =================
__global__ __launch_bounds__(256) void k3_pass2(const float* __restrict__ F_path,
                                                const float* __restrict__ F_gene,
                                                const float* __restrict__ gene_W,
                                                const float* __restrict__ gene_ln_g,
                                                const float* __restrict__ gene_ln_b,
                                                float* __restrict__ ws) {
    __shared__ __align__(16) float lds[4096];  // 16 KB, multi-purpose
    int t = threadIdx.x, blk = blockIdx.x;
    if (blk < 1024) {
        int b = blk >> 6, chunk = blk & 63;
        int w = t >> 6, lane = t & 63;
        float4 zacc[NPE][4];
#pragma unroll
        for (int e = 0; e < NPE; e++)
#pragma unroll
            for (int j = 0; j < 4; j++) zacc[e][j] = make_float4(0.f, 0.f, 0.f, 0.f);
        for (int i = 0; i < 16; i++) {
            int n = chunk * 64 + w * 16 + i;
            const float4* rowp = (const float4*)(F_path + ((size_t)(b * NTOK + n)) * PIN);
            float4 x[4];
#pragma unroll
            for (int j = 0; j < 4; j++) x[j] = rowp[lane + 64 * j];
            float m = ws[WS_MEAN + b * NTOK + n];
            float r = ws[WS_RSTD + b * NTOK + n];
            float ar[NPE];
#pragma unroll
            for (int e = 0; e < NPE; e++) ar[e] = ws[WS_S + (e * BB + b) * NTOK + n] * r;
#pragma unroll
            for (int e = 0; e < NPE; e++) {
#pragma unroll
                for (int j = 0; j < 4; j++) {
                    zacc[e][j].x += ar[e] * (x[j].x - m);
                    zacc[e][j].y += ar[e] * (x[j].y - m);
                    zacc[e][j].z += ar[e] * (x[j].z - m);
                    zacc[e][j].w += ar[e] * (x[j].w - m);
                }
            }
        }
        float4* l4 = (float4*)lds;
        for (int e = 0; e < NPE; e++) {
            __syncthreads();
#pragma unroll
            for (int j = 0; j < 4; j++) l4[w * (PIN / 4) + lane + 64 * j] = zacc[e][j];
            __syncthreads();
            float4 a = l4[t], bq = l4[256 + t], c = l4[512 + t], d = l4[768 + t];
            atomicAdd(ws + WS_Z + (e * BB + b) * PIN + 4 * t + 0, a.x + bq.x + c.x + d.x);
            atomicAdd(ws + WS_Z + (e * BB + b) * PIN + 4 * t + 1, a.y + bq.y + c.y + d.y);
            atomicAdd(ws + WS_Z + (e * BB + b) * PIN + 4 * t + 2, a.z + bq.z + c.z + d.z);
            atomicAdd(ws + WS_Z + (e * BB + b) * PIN + 4 * t + 3, a.w + bq.w + c.w + d.w);
        }
    } else {
        // gene projection: Xg_acc[b,d] += sum_k y[b,k]*gene_W[k,d], k-chunk of 256
        int k0 = (blk - 1024) * 256;
        for (int b = 0; b < BB; b++) {
            float x = F_gene[(size_t)b * GIN + k0 + t];
            float m = ws[WS_GMEAN + b], r = ws[WS_GRSTD + b];
            lds[b * 256 + t] = (x - m) * r * gene_ln_g[k0 + t] + gene_ln_b[k0 + t];
        }
        __syncthreads();
        float acc0[BB], acc1[BB];
#pragma unroll
        for (int b = 0; b < BB; b++) { acc0[b] = 0.f; acc1[b] = 0.f; }
        int d0 = t, d1 = t + 256;
        for (int kk = 0; kk < 256; kk++) {
            float w0 = gene_W[(size_t)(k0 + kk) * DIM + d0];
            float w1 = gene_W[(size_t)(k0 + kk) * DIM + d1];
#pragma unroll
            for (int b = 0; b < BB; b++) {
                float y = lds[b * 256 + kk];
                acc0[b] += y * w0; acc1[b] += y * w1;
            }
        }
        for (int b = 0; b < BB; b++) {
            atomicAdd(ws + WS_XG + b * DIM + d0, acc0[b]);
            atomicAdd(ws + WS_XG + b * DIM + d1, acc1[b]);
        }
    }
}

// ================= K4: pooled & Xp_mean via the 80x1024x512 mini-GEMM =================
__global__ __launch_bounds__(256) void k4_pool(const float* __restrict__ path_W,
                                               const float* __restrict__ path_ln_g,
                                               const float* __restrict__ path_ln_b,
                                               const float* __restrict__ path_b,
                                               float* __restrict__ ws) {
    __shared__ float rows[4 * PIN];  // 16 KB
    int blk = blockIdx.x, t = threadIdx.x;
    int rg = blk >> 1, dt = blk & 1;
    for (int i = t; i < 4 * PIN; i += 256) {
        int j = i >> 10, k = i & 1023;
        int r = rg * 4 + j;
        float v = (r < 64) ? ws[WS_Z + r * PIN + k]
                           : ws[WS_SUMXN + (r - 64) * PIN + k] * (1.f / NTOK);
        rows[i] = v * path_ln_g[k] + path_ln_b[k];
    }
    __syncthreads();
    int d = dt * 256 + t;
    float acc[4] = {0.f, 0.f, 0.f, 0.f};
    for (int k = 0; k < PIN; k++) {
        float wv = path_W[(size_t)k * DIM + d];
#pragma unroll
        for (int j = 0; j < 4; j++) acc[j] += rows[j * PIN + k] * wv;
    }
    float pb = path_b[d];
#pragma unroll
    for (int j = 0; j < 4; j++) {
        int r = rg * 4 + j;
        float o = acc[j] + pb;
        if (r < 64) ws[WS_POOLED + r * DIM + d] = o;
        else        ws[WS_XPMEAN + (r - 64) * DIM + d] = o;
    }
}

// ================= K5: row LN + gating + expert-input affine =================
__global__ __launch_bounds__(256) void k5_rows(const float* __restrict__ gene_b,
    const float* __restrict__ gg_ln_g, const float* __restrict__ gg_ln_b,
    const float* __restrict__ gg_W, const float* __restrict__ gg_b,
    const float* __restrict__ pg_ln_g, const float* __restrict__ pg_ln_b,
    const float* __restrict__ pg_W, const float* __restrict__ pg_b,
    const float* __restrict__ g_ln_g, const float* __restrict__ g_ln_b,
    const float* __restrict__ p_ln_g, const float* __restrict__ p_ln_b,
    float* __restrict__ ws) {
    int blk = blockIdx.x, t = threadIdx.x;
    __shared__ float sc[8];
    __shared__ float sc2[16];
    int c0 = t, c1 = t + 256;
    int w = t >> 6, lane = t & 63;
    float v0, v1;
    int type, b = 0, r = 0;
    if (blk < 16) {
        type = 0; b = blk;
        v0 = ws[WS_XG + b * DIM + c0] + gene_b[c0];
        v1 = ws[WS_XG + b * DIM + c1] + gene_b[c1];
    } else if (blk < 32) {
        type = 1; b = blk - 16;
        v0 = ws[WS_XPMEAN + b * DIM + c0];
        v1 = ws[WS_XPMEAN + b * DIM + c1];
    } else {
        type = 2; r = blk - 32;
        v0 = ws[WS_POOLED + r * DIM + c0];
        v1 = ws[WS_POOLED + r * DIM + c1];
    }
    float s1 = wsum(v0 + v1), s2 = wsum(v0 * v0 + v1 * v1);
    if (lane == 0) { sc[w] = s1; sc[4 + w] = s2; }
    __syncthreads();
    s1 = sc[0] + sc[1] + sc[2] + sc[3];
    s2 = sc[4] + sc[5] + sc[6] + sc[7];
    float m = s1 / DIM, var = s2 / DIM - m * m, rs = rsqrtf(var + EPS);
    float xn0 = (v0 - m) * rs, xn1 = (v1 - m) * rs;
    if (type == 0) {
#pragma unroll
        for (int e = 0; e < NGE; e++) {
            ws[WS_UG + (e * BB + b) * DIM + c0] = xn0 * g_ln_g[e * DIM + c0] + g_ln_b[e * DIM + c0];
            ws[WS_UG + (e * BB + b) * DIM + c1] = xn1 * g_ln_g[e * DIM + c1] + g_ln_b[e * DIM + c1];
        }
        float t0 = xn0 * gg_ln_g[c0] + gg_ln_b[c0];
        float t1 = xn1 * gg_ln_g[c1] + gg_ln_b[c1];
        float l[4];
#pragma unroll
        for (int e = 0; e < 4; e++) l[e] = wsum(t0 * gg_W[c0 * 4 + e] + t1 * gg_W[c1 * 4 + e]);
        if (lane == 0)
#pragma unroll
            for (int e = 0; e < 4; e++) sc2[w * 4 + e] = l[e];
        __syncthreads();
        if (t == 0) {
            float lg[4], mx = -1e30f;
#pragma unroll
            for (int e = 0; e < 4; e++) {
                lg[e] = sc2[e] + sc2[4 + e] + sc2[8 + e] + sc2[12 + e] + gg_b[e];
                mx = fmaxf(mx, lg[e]);
            }
            float sum = 0.f;
#pragma unroll
            for (int e = 0; e < 4; e++) { lg[e] = __expf(lg[e] - mx); sum += lg[e]; }
#pragma unroll
            for (int e = 0; e < 4; e++) ws[WS_WG + b * NGE + e] = lg[e] / sum;
        }
    } else if (type == 1) {
        float t0 = xn0 * pg_ln_g[c0] + pg_ln_b[c0];
        float t1 = xn1 * pg_ln_g[c1] + pg_ln_b[c1];
        float l[4];
#pragma unroll
        for (int e = 0; e < 4; e++) l[e] = wsum(t0 * pg_W[c0 * 4 + e] + t1 * pg_W[c1 * 4 + e]);
        if (lane == 0)
#pragma unroll
            for (int e = 0; e < 4; e++) sc2[w * 4 + e] = l[e];
        __syncthreads();
        if (t == 0) {
            float lg[4], mx = -1e30f;
#pragma unroll
            for (int e = 0; e < 4; e++) {
                lg[e] = sc2[e] + sc2[4 + e] + sc2[8 + e] + sc2[12 + e] + pg_b[e];
                mx = fmaxf(mx, lg[e]);
            }
            float sum = 0.f;
#pragma unroll
            for (int e = 0; e < 4; e++) { lg[e] = __expf(lg[e] - mx); sum += lg[e]; }
#pragma unroll
            for (int e = 0; e < 4; e++) ws[WS_WP + b * NPE + e] = lg[e] / sum;
        }
    } else {
        int e = r >> 4;
        ws[WS_UP + r * DIM + c0] = xn0 * p_ln_g[e * DIM + c0] + p_ln_b[e * DIM + c0];
        ws[WS_UP + r * DIM + c1] = xn1 * p_ln_g[e * DIM + c1] + p_ln_b[e * DIM + c1];
    }
}

// ================= expert MLP layer1: H = GELU(U @ W1 + b1) =================
// grid: halfBlk (set0) + rest (set1); per set: nE*32 blocks; block = 64 h-cols x 4 k-chunks
__global__ __launch_bounds__(256) void k_mlp1(const float* __restrict__ U0, const float* __restrict__ W10,
                                              const float* __restrict__ b10, float* __restrict__ H0,
                                              const float* __restrict__ U1, const float* __restrict__ W11,
                                              const float* __restrict__ b11, float* __restrict__ H1,
                                              int halfBlk) {
    __shared__ float smem[8192];  // 32 KB
    int blk = blockIdx.x, t = threadIdx.x;
    const float* U; const float* W1; const float* b1; float* H;
    int lb;
    if (blk < halfBlk) { U = U0; W1 = W10; b1 = b10; H = H0; lb = blk; }
    else               { U = U1; W1 = W11; b1 = b11; H = H1; lb = blk - halfBlk; }
    int e = lb >> 5, ht = lb & 31;
    const float* Ue = U + (size_t)e * BB * DIM;
    for (int i = t; i < BB * DIM; i += 256) smem[i] = Ue[i];
    __syncthreads();
    int hl = t & 63, kc = t >> 6;
    int h = ht * 64 + hl;
    const float* w1p = W1 + (size_t)e * DIM * HID + h;
    float acc[BB];
#pragma unroll
    for (int b = 0; b < BB; b++) acc[b] = 0.f;
    for (int k = kc * 128; k < kc * 128 + 128; k++) {
        float wv = w1p[(size_t)k * HID];
#pragma unroll
        for (int b = 0; b < BB; b++) acc[b] += smem[b * DIM + k] * wv;
    }
    __syncthreads();
#pragma unroll
    for (int b = 0; b < BB; b++) smem[t * BB + b] = acc[b];
    __syncthreads();
    if (t < 64) {
        int hh = ht * 64 + t;
        float bv = b1[e * HID + hh];
#pragma unroll
        for (int b = 0; b < BB; b++) {
            float s = smem[(0 * 64 + t) * BB + b] + smem[(1 * 64 + t) * BB + b] +
                      smem[(2 * 64 + t) * BB + b] + smem[(3 * 64 + t) * BB + b] + bv;
            H[(size_t)(e * BB + b) * HID + hh] = gelu_exact(s);
        }
    }
}

// ================= expert MLP layer2 + gate-weighted accumulate =================
// per set: nE*4*8 blocks (e, b-quarter, d-tile); block = 64 d-cols x 4 k-chunks of 512
__global__ __launch_bounds__(256) void k_mlp2(const float* __restrict__ H0, const float* __restrict__ W20,
                                              const float* __restrict__ b20, const float* __restrict__ gate0,
                                              int ng0, float* __restrict__ out0,
                                              const float* __restrict__ H1, const float* __restrict__ W21,
                                              const float* __restrict__ b21, const float* __restrict__ gate1,
                                              int ng1, float* __restrict__ out1,
                                              int halfBlk) {
    __shared__ float smem[8192];  // 32 KB
    int blk = blockIdx.x, t = threadIdx.x;
    const float* H; const float* W2; const float* b2; const float* gate; float* outp;
    int ng, lb;
    if (blk < halfBlk) { H = H0; W2 = W20; b2 = b20; gate = gate0; ng = ng0; outp = out0; lb = blk; }
    else               { H = H1; W2 = W21; b2 = b21; gate = gate1; ng = ng1; outp = out1; lb = blk - halfBlk; }
    int e = lb >> 5, bq = (lb >> 3) & 3, dt = lb & 7;
    const float* He = H + (size_t)(e * BB + bq * 4) * HID;
    for (int i = t; i < 4 * HID; i += 256) smem[i] = He[i];
    __syncthreads();
    int dl = t & 63, kc = t >> 6;
    int d = dt * 64 + dl;
    const float* w2p = W2 + (size_t)e * HID * DIM + d;
    float acc[4] = {0.f, 0.f, 0.f, 0.f};
    for (int k = kc * 512; k < kc * 512 + 512; k++) {
        float wv = w2p[(size_t)k * DIM];
#pragma unroll
        for (int b = 0; b < 4; b++) acc[b] += smem[b * HID + k] * wv;
    }
    __syncthreads();
#pragma unroll
    for (int b = 0; b < 4; b++) smem[t * 4 + b] = acc[b];
    __syncthreads();
    if (t < 64) {
        int dd = dt * 64 + t;
        float bv = b2[e * DIM + dd];
#pragma unroll
        for (int b = 0; b < 4; b++) {
            float s = smem[(0 * 64 + t) * 4 + b] + smem[(1 * 64 + t) * 4 + b] +
                      smem[(2 * 64 + t) * 4 + b] + smem[(3 * 64 + t) * 4 + b] + bv;
            int bg = bq * 4 + b;
            atomicAdd(outp + (size_t)bg * DIM + dd, s * gate[bg * ng + e]);
        }
    }
}

// ================= K8: fusion — LN(fused), wf, fused_in, LN(fused_in) -> Uf =================
__global__ __launch_bounds__(256) void k8_fusion(const float* __restrict__ fg_ln_g, const float* __restrict__ fg_ln_b,
                                                 const float* __restrict__ fg_W, const float* __restrict__ fg_b,
                                                 const float* __restrict__ fin_ln_g, const float* __restrict__ fin_ln_b,
                                                 const float* __restrict__ fin_W, const float* __restrict__ fin_b,
                                                 const float* __restrict__ f_ln_g, const float* __restrict__ f_ln_b,
                                                 float* __restrict__ ws) {
    __shared__ float tl[1024];
    __shared__ float sc[8];
    __shared__ float sc2[8];
    int b = blockIdx.x, t = threadIdx.x;
    int w = t >> 6, lane = t & 63;
    float v[4];
    v[0] = ws[WS_FG + b * DIM + t];       // col t
    v[1] = ws[WS_FG + b * DIM + t + 256]; // col t+256
    v[2] = ws[WS_FP + b * DIM + t];       // col t+512
    v[3] = ws[WS_FP + b * DIM + t + 256]; // col t+768
    float s1 = wsum(v[0] + v[1] + v[2] + v[3]);
    float s2 = wsum(v[0] * v[0] + v[1] * v[1] + v[2] * v[2] + v[3] * v[3]);
    if (lane == 0) { sc[w] = s1; sc[4 + w] = s2; }
    __syncthreads();
    s1 = sc[0] + sc[1] + sc[2] + sc[3];
    s2 = sc[4] + sc[5] + sc[6] + sc[7];
    float m = s1 / (2 * DIM), var = s2 / (2 * DIM) - m * m, rs = rsqrtf(var + EPS);
    float l0 = 0.f, l1 = 0.f;
    int cols[4] = {t, t + 256, t + 512, t + 768};
#pragma unroll
    for (int j = 0; j < 4; j++) {
        int c = cols[j];
        float xn = (v[j] - m) * rs;
        float tf = xn * fg_ln_g[c] + fg_ln_b[c];
        l0 += tf * fg_W[c * 2 + 0];
        l1 += tf * fg_W[c * 2 + 1];
        tl[c] = xn * fin_ln_g[c] + fin_ln_b[c];
    }
    l0 = wsum(l0); l1 = wsum(l1);
    if (lane == 0) { sc2[w] = l0; sc2[4 + w] = l1; }
    __syncthreads();   // tl ready + sc2 ready + sc reads done
    if (t == 0) {
        float L0 = sc2[0] + sc2[1] + sc2[2] + sc2[3] + fg_b[0];
        float L1 = sc2[4] + sc2[5] + sc2[6] + sc2[7] + fg_b[1];
        float mx = fmaxf(L0, L1);
        float p0 = __expf(L0 - mx), p1 = __expf(L1 - mx);
        float inv = 1.f / (p0 + p1);
        ws[WS_WF + b * NFE + 0] = p0 * inv;
        ws[WS_WF + b * NFE + 1] = p1 * inv;
    }
    // fused_in = tl @ fin_W + fin_b
    int d0 = t, d1 = t + 256;
    float a0 = 0.f, a1 = 0.f;
    for (int k = 0; k < 2 * DIM; k++) {
        float tv = tl[k];
        a0 += tv * fin_W[(size_t)k * DIM + d0];
        a1 += tv * fin_W[(size_t)k * DIM + d1];
    }
    a0 += fin_b[d0]; a1 += fin_b[d1];
    // LN(fused_in)
    float t1s = wsum(a0 + a1), t2s = wsum(a0 * a0 + a1 * a1);
    __syncthreads();  // sc reuse safety
    if (lane == 0) { sc[w] = t1s; sc[4 + w] = t2s; }
    __syncthreads();
    t1s = sc[0] + sc[1] + sc[2] + sc[3];
    t2s = sc[4] + sc[5] + sc[6] + sc[7];
    float m2 = t1s / DIM, var2 = t2s / DIM - m2 * m2, rs2 = rsqrtf(var2 + EPS);
    float x0 = (a0 - m2) * rs2, x1 = (a1 - m2) * rs2;
#pragma unroll
    for (int e = 0; e < NFE; e++) {
        ws[WS_UF + (e * BB + b) * DIM + d0] = x0 * f_ln_g[e * DIM + d0] + f_ln_b[e * DIM + d0];
        ws[WS_UF + (e * BB + b) * DIM + d1] = x1 * f_ln_g[e * DIM + d1] + f_ln_b[e * DIM + d1];
    }
}

// ================= K11: classifier + sigmoid + cumprod =================
__global__ void k11_out(const float* __restrict__ cls_W, const float* __restrict__ cls_b,
                        const float* __restrict__ ws, float* __restrict__ out) {
    __shared__ float hz[64];
    int t = threadIdx.x;  // 64 threads
    int b = t >> 2, c = t & 3;
    const float* x = ws + WS_FIMMF + b * DIM;
    float acc = 0.f;
    for (int k = 0; k < DIM; k++) acc += x[k] * cls_W[k * NCLS + c];
    acc += cls_b[c];
    float h = 1.f / (1.f + __expf(-acc));
    hz[t] = h;
    __syncthreads();
    float S = 1.f;
    for (int j = 0; j <= c; j++) S *= (1.f - hz[b * 4 + j]);
    out[t] = h;
    out[64 + t] = S;
}

extern "C" void kernel_launch(void* const* d_in, const int* in_sizes, int n_in,
                              void* d_out, int out_size, void* d_ws, size_t ws_size,
                              hipStream_t stream) {
    (void)in_sizes; (void)n_in; (void)out_size; (void)ws_size;
    const float* F_gene    = (const float*)d_in[0];
    const float* F_path    = (const float*)d_in[1];
    const float* gene_ln_g = (const float*)d_in[2];
    const float* gene_ln_b = (const float*)d_in[3];
    const float* gene_W    = (const float*)d_in[4];
    const float* gene_b    = (const float*)d_in[5];
    const float* path_ln_g = (const float*)d_in[6];
    const float* path_ln_b = (const float*)d_in[7];
    const float* path_W    = (const float*)d_in[8];
    const float* path_b    = (const float*)d_in[9];
    const float* g_ln_g    = (const float*)d_in[10];
    const float* g_ln_b    = (const float*)d_in[11];
    const float* g_W1      = (const float*)d_in[12];
    const float* g_b1      = (const float*)d_in[13];
    const float* g_W2      = (const float*)d_in[14];
    const float* g_b2      = (const float*)d_in[15];
    const float* p_q       = (const float*)d_in[16];
    const float* p_ln_g    = (const float*)d_in[17];
    const float* p_ln_b    = (const float*)d_in[18];
    const float* p_W1      = (const float*)d_in[19];
    const float* p_b1      = (const float*)d_in[20];
    const float* p_W2      = (const float*)d_in[21];
    const float* p_b2      = (const float*)d_in[22];
    const float* f_ln_g    = (const float*)d_in[23];
    const float* f_ln_b    = (const float*)d_in[24];
    const float* f_W1      = (const float*)d_in[25];
    const float* f_b1      = (const float*)d_in[26];
    const float* f_W2      = (const float*)d_in[27];
    const float* f_b2      = (const float*)d_in[28];
    const float* gg_ln_g   = (const float*)d_in[29];
    const float* gg_ln_b   = (const float*)d_in[30];
    const float* gg_W      = (const float*)d_in[31];
    const float* gg_b      = (const float*)d_in[32];
    const float* pg_ln_g   = (const float*)d_in[33];
    const float* pg_ln_b   = (const float*)d_in[34];
    const float* pg_W      = (const float*)d_in[35];
    const float* pg_b      = (const float*)d_in[36];
    const float* fg_ln_g   = (const float*)d_in[37];
    const float* fg_ln_b   = (const float*)d_in[38];
    const float* fg_W      = (const float*)d_in[39];
    const float* fg_b      = (const float*)d_in[40];
    const float* fin_ln_g  = (const float*)d_in[41];
    const float* fin_ln_b  = (const float*)d_in[42];
    const float* fin_W     = (const float*)d_in[43];
    const float* fin_b     = (const float*)d_in[44];
    const float* cls_W     = (const float*)d_in[45];
    const float* cls_b     = (const float*)d_in[46];
    float* ws  = (float*)d_ws;
    float* out = (float*)d_out;

    k0_init<<<132, 256, 0, stream>>>(F_gene, path_W, p_q, path_ln_g, ws);
    k1_pass1<<<1024, 256, 0, stream>>>(F_path, ws);
    k2_softmax<<<64, 256, 0, stream>>>(ws);
    k3_pass2<<<1040, 256, 0, stream>>>(F_path, F_gene, gene_W, gene_ln_g, gene_ln_b, ws);
    k4_pool<<<40, 256, 0, stream>>>(path_W, path_ln_g, path_ln_b, path_b, ws);
    k5_rows<<<96, 256, 0, stream>>>(gene_b, gg_ln_g, gg_ln_b, gg_W, gg_b,
                                    pg_ln_g, pg_ln_b, pg_W, pg_b,
                                    g_ln_g, g_ln_b, p_ln_g, p_ln_b, ws);
    k_mlp1<<<256, 256, 0, stream>>>(ws + WS_UG, g_W1, g_b1, ws + WS_HG,
                                    ws + WS_UP, p_W1, p_b1, ws + WS_HP, 128);
    k_mlp2<<<256, 256, 0, stream>>>(ws + WS_HG, g_W2, g_b2, ws + WS_WG, NGE, ws + WS_FG,
                                    ws + WS_HP, p_W2, p_b2, ws + WS_WP, NPE, ws + WS_FP, 128);
    k8_fusion<<<16, 256, 0, stream>>>(fg_ln_g, fg_ln_b, fg_W, fg_b,
                                      fin_ln_g, fin_ln_b, fin_W, fin_b,
                                      f_ln_g, f_ln_b, ws);
    k_mlp1<<<64, 256, 0, stream>>>(ws + WS_UF, f_W1, f_b1, ws + WS_HF,
                                   ws + WS_UF, f_W1, f_b1, ws + WS_HF, 64);
    k_mlp2<<<64, 256, 0, stream>>>(ws + WS_HF, f_W2, f_b2, ws + WS_WF, NFE, ws + WS_FIMMF,
                                   ws + WS_HF, f_W2, f_b2, ws + WS_WF, NFE, ws + WS_FIMMF, 64);
    k11_out<<<1, 64, 0, stream>>>(cls_W, cls_b, ws, out);
}

// Round 3
// 897.323 us; speedup vs baseline: 1.8647x; 1.8647x over previous
//
#include <hip/hip_runtime.h>
#include <math.h>

#define BB 16
#define NTOK 4096
#define DIM 512
#define HID 2048
#define NGE 4
#define NPE 4
#define NFE 2
#define GIN 4096
#define PIN 1024
#define NCLS 4
#define EPS 1e-5f

// ---- workspace layout (float offsets) ----
// zero-initialized accumulator region [0, ZERO_TOT):
#define WS_SUMXN   0            // BB*PIN    = 16384
#define WS_Z       16384        // NPE*BB*PIN= 65536
#define WS_XG      81920        // 8192
#define WS_FG      90112        // 8192
#define WS_FP      98304        // 8192
#define WS_FIMMF   106496       // 8192
#define WS_POOLED  114688       // 32768  (pooled GEMM accum, no path_b)
#define WS_XPMEAN  147456       // 8192   (xp-mean GEMM accum, no path_b)
#define WS_FIN     155648       // 8192   (fused_in GEMM accum, no fin_b)
#define WS_HG      163840       // NGE*BB*HID = 131072 (pre-act accum)
#define WS_HP      294912       // 131072               (contiguous after HG!)
#define WS_HF      425984       // NFE*BB*HID = 65536
#define ZERO_TOT   491520       // 480 blocks x 1024 floats
// scratch (not zeroed):
#define WS_MEAN    491520       // BB*NTOK = 65536
#define WS_RSTD    557056       // 65536
#define WS_S       622592       // NPE*BB*NTOK = 262144
#define WS_QPROJ   884736       // NPE*PIN = 4096
#define WS_GMEAN   888832       // 16
#define WS_GRSTD   888848       // 16
#define WS_WG      888864       // 64
#define WS_WP      888928       // 64
#define WS_WF      888992       // 32
#define WS_UG      889024       // 32768
#define WS_UP      921792       // 32768
#define WS_UF      954560       // 16384
#define WS_TL      970944       // BB*2*DIM = 16384
#define WS_END     987328       // ~3.95 MB

__device__ __forceinline__ float wsum(float v) {
#pragma unroll
    for (int o = 32; o > 0; o >>= 1) v += __shfl_xor(v, o);
    return v;
}
__device__ __forceinline__ float wmax(float v) {
#pragma unroll
    for (int o = 32; o > 0; o >>= 1) v = fmaxf(v, __shfl_xor(v, o));
    return v;
}
__device__ __forceinline__ float gelu_exact(float x) {
    return 0.5f * x * (1.0f + erff(x * 0.70710678118654752f));
}

// ============ K0: zero accumulators | qproj (wave-per-row) | gene row stats ============
__global__ __launch_bounds__(256) void k0_init(const float* __restrict__ F_gene,
                                               const float* __restrict__ path_W,
                                               const float* __restrict__ p_q,
                                               const float* __restrict__ path_ln_g,
                                               float* __restrict__ ws) {
    int blk = blockIdx.x, t = threadIdx.x;
    if (blk < 480) {
        ((float4*)ws)[blk * 256 + t] = make_float4(0.f, 0.f, 0.f, 0.f);
    } else if (blk < 496) {
        // qproj[e,k] = path_ln_g[k] * sum_d path_W[k,d] * p_q[e,d]; wave per row k
        __shared__ __align__(16) float pq[NPE * DIM];
        for (int i = t; i < NPE * DIM; i += 256) pq[i] = p_q[i];
        __syncthreads();
        int w = t >> 6, lane = t & 63;
        const float4* pq4 = (const float4*)pq;  // 128 float4 per expert
        for (int i = 0; i < 16; i++) {
            int k = (blk - 480) * 64 + w * 16 + i;
            const float4* wp4 = (const float4*)(path_W + (size_t)k * DIM);
            float4 x0 = wp4[lane], x1 = wp4[lane + 64];
            float sc[NPE];
#pragma unroll
            for (int e = 0; e < NPE; e++) {
                float4 q0 = pq4[e * 128 + lane], q1 = pq4[e * 128 + lane + 64];
                float d = x0.x * q0.x + x0.y * q0.y + x0.z * q0.z + x0.w * q0.w +
                          x1.x * q1.x + x1.y * q1.y + x1.z * q1.z + x1.w * q1.w;
                sc[e] = wsum(d);
            }
            if (lane == 0) {
                float g = path_ln_g[k];
#pragma unroll
                for (int e = 0; e < NPE; e++) ws[WS_QPROJ + e * PIN + k] = g * sc[e];
            }
        }
    } else {
        // gene row stats (16 rows of 4096)
        int b = blk - 496;
        const float4* row = (const float4*)(F_gene + (size_t)b * GIN);
        float s1 = 0.f, s2 = 0.f;
        for (int i = t; i < GIN / 4; i += 256) {
            float4 v = row[i];
            s1 += v.x + v.y + v.z + v.w;
            s2 += v.x * v.x + v.y * v.y + v.z * v.z + v.w * v.w;
        }
        __shared__ float sc[8];
        s1 = wsum(s1); s2 = wsum(s2);
        int w = t >> 6;
        if ((t & 63) == 0) { sc[w] = s1; sc[4 + w] = s2; }
        __syncthreads();
        if (t == 0) {
            float S1 = sc[0] + sc[1] + sc[2] + sc[3];
            float S2 = sc[4] + sc[5] + sc[6] + sc[7];
            float m = S1 / GIN;
            float var = S2 / GIN - m * m;
            ws[WS_GMEAN + b] = m;
            ws[WS_GRSTD + b] = rsqrtf(var + EPS);
        }
    }
}

// ============ K1: F_path pass1 — LN stats, score dots, sum of xn ============
__global__ __launch_bounds__(256) void k1_pass1(const float* __restrict__ F_path,
                                                float* __restrict__ ws) {
    __shared__ __align__(16) float qlds[NPE * PIN];  // 16 KB
    __shared__ __align__(16) float comb[4 * PIN];    // 16 KB
    int t = threadIdx.x;
    for (int i = t; i < NPE * PIN; i += 256) qlds[i] = ws[WS_QPROJ + i];
    __syncthreads();
    int blk = blockIdx.x;
    int b = blk >> 6, chunk = blk & 63;
    int w = t >> 6, lane = t & 63;
    const float4* qp4 = (const float4*)qlds;
    float4 sxn[4];
#pragma unroll
    for (int j = 0; j < 4; j++) sxn[j] = make_float4(0.f, 0.f, 0.f, 0.f);
    for (int i = 0; i < 16; i++) {
        int n = chunk * 64 + w * 16 + i;
        const float4* rowp = (const float4*)(F_path + ((size_t)(b * NTOK + n)) * PIN);
        float4 x[4];
#pragma unroll
        for (int j = 0; j < 4; j++) x[j] = rowp[lane + 64 * j];
        float s1 = 0.f, s2 = 0.f;
#pragma unroll
        for (int j = 0; j < 4; j++) {
            s1 += x[j].x + x[j].y + x[j].z + x[j].w;
            s2 += x[j].x * x[j].x + x[j].y * x[j].y + x[j].z * x[j].z + x[j].w * x[j].w;
        }
        s1 = wsum(s1); s2 = wsum(s2);
        float m = s1 * (1.f / PIN);
        float var = s2 * (1.f / PIN) - m * m;
        float r = rsqrtf(var + EPS);
        float sc[NPE];
#pragma unroll
        for (int e = 0; e < NPE; e++) {
            float d = 0.f;
#pragma unroll
            for (int j = 0; j < 4; j++) {
                float4 q = qp4[e * (PIN / 4) + lane + 64 * j];
                d += (x[j].x - m) * q.x + (x[j].y - m) * q.y +
                     (x[j].z - m) * q.z + (x[j].w - m) * q.w;
            }
            sc[e] = wsum(d) * r;
        }
#pragma unroll
        for (int j = 0; j < 4; j++) {
            sxn[j].x += (x[j].x - m) * r;
            sxn[j].y += (x[j].y - m) * r;
            sxn[j].z += (x[j].z - m) * r;
            sxn[j].w += (x[j].w - m) * r;
        }
        if (lane == 0) {
            ws[WS_MEAN + b * NTOK + n] = m;
            ws[WS_RSTD + b * NTOK + n] = r;
#pragma unroll
            for (int e = 0; e < NPE; e++) ws[WS_S + (e * BB + b) * NTOK + n] = sc[e];
        }
    }
    float4* comb4 = (float4*)comb;
#pragma unroll
    for (int j = 0; j < 4; j++) comb4[w * (PIN / 4) + lane + 64 * j] = sxn[j];
    __syncthreads();
    {
        float4 a = comb4[t], bq = comb4[256 + t], c = comb4[512 + t], d = comb4[768 + t];
        atomicAdd(ws + WS_SUMXN + b * PIN + 4 * t + 0, a.x + bq.x + c.x + d.x);
        atomicAdd(ws + WS_SUMXN + b * PIN + 4 * t + 1, a.y + bq.y + c.y + d.y);
        atomicAdd(ws + WS_SUMXN + b * PIN + 4 * t + 2, a.z + bq.z + c.z + d.z);
        atomicAdd(ws + WS_SUMXN + b * PIN + 4 * t + 3, a.w + bq.w + c.w + d.w);
    }
}

// ============ K2: softmax over n for each (e,b) ============
__global__ __launch_bounds__(256) void k2_softmax(float* __restrict__ ws) {
    int row = blockIdx.x;
    float* s = ws + WS_S + (size_t)row * NTOK;
    int t = threadIdx.x, w = t >> 6, lane = t & 63;
    __shared__ float sc[4];
    float4 v[4];
    float mx = -1e30f;
#pragma unroll
    for (int j = 0; j < 4; j++) {
        v[j] = ((float4*)s)[t + j * 256];
        mx = fmaxf(mx, fmaxf(fmaxf(v[j].x, v[j].y), fmaxf(v[j].z, v[j].w)));
    }
    mx = wmax(mx);
    if (lane == 0) sc[w] = mx;
    __syncthreads();
    mx = fmaxf(fmaxf(sc[0], sc[1]), fmaxf(sc[2], sc[3]));
    __syncthreads();
    float sum = 0.f;
#pragma unroll
    for (int j = 0; j < 4; j++) {
        v[j].x = __expf(v[j].x - mx); v[j].y = __expf(v[j].y - mx);
        v[j].z = __expf(v[j].z - mx); v[j].w = __expf(v[j].w - mx);
        sum += v[j].x + v[j].y + v[j].z + v[j].w;
    }
    sum = wsum(sum);
    if (lane == 0) sc[w] = sum;
    __syncthreads();
    float inv = 1.f / (sc[0] + sc[1] + sc[2] + sc[3]);
#pragma unroll
    for (int j = 0; j < 4; j++) {
        v[j].x *= inv; v[j].y *= inv; v[j].z *= inv; v[j].w *= inv;
        ((float4*)s)[t + j * 256] = v[j];
    }
}

// ============ K3: F_path pass2 (z = attn-weighted sum of xn) + gene GEMM ============
__global__ __launch_bounds__(256) void k3_pass2(const float* __restrict__ F_path,
                                                const float* __restrict__ F_gene,
                                                const float* __restrict__ gene_W,
                                                const float* __restrict__ gene_ln_g,
                                                const float* __restrict__ gene_ln_b,
                                                float* __restrict__ ws) {
    __shared__ __align__(16) float lds[4096];
    int t = threadIdx.x, blk = blockIdx.x;
    if (blk < 1024) {
        int b = blk >> 6, chunk = blk & 63;
        int w = t >> 6, lane = t & 63;
        float4 zacc[NPE][4];
#pragma unroll
        for (int e = 0; e < NPE; e++)
#pragma unroll
            for (int j = 0; j < 4; j++) zacc[e][j] = make_float4(0.f, 0.f, 0.f, 0.f);
        for (int i = 0; i < 16; i++) {
            int n = chunk * 64 + w * 16 + i;
            const float4* rowp = (const float4*)(F_path + ((size_t)(b * NTOK + n)) * PIN);
            float4 x[4];
#pragma unroll
            for (int j = 0; j < 4; j++) x[j] = rowp[lane + 64 * j];
            float m = ws[WS_MEAN + b * NTOK + n];
            float r = ws[WS_RSTD + b * NTOK + n];
            float ar[NPE];
#pragma unroll
            for (int e = 0; e < NPE; e++) ar[e] = ws[WS_S + (e * BB + b) * NTOK + n] * r;
#pragma unroll
            for (int e = 0; e < NPE; e++) {
#pragma unroll
                for (int j = 0; j < 4; j++) {
                    zacc[e][j].x += ar[e] * (x[j].x - m);
                    zacc[e][j].y += ar[e] * (x[j].y - m);
                    zacc[e][j].z += ar[e] * (x[j].z - m);
                    zacc[e][j].w += ar[e] * (x[j].w - m);
                }
            }
        }
        float4* l4 = (float4*)lds;
        for (int e = 0; e < NPE; e++) {
            __syncthreads();
#pragma unroll
            for (int j = 0; j < 4; j++) l4[w * (PIN / 4) + lane + 64 * j] = zacc[e][j];
            __syncthreads();
            float4 a = l4[t], bq = l4[256 + t], c = l4[512 + t], d = l4[768 + t];
            atomicAdd(ws + WS_Z + (e * BB + b) * PIN + 4 * t + 0, a.x + bq.x + c.x + d.x);
            atomicAdd(ws + WS_Z + (e * BB + b) * PIN + 4 * t + 1, a.y + bq.y + c.y + d.y);
            atomicAdd(ws + WS_Z + (e * BB + b) * PIN + 4 * t + 2, a.z + bq.z + c.z + d.z);
            atomicAdd(ws + WS_Z + (e * BB + b) * PIN + 4 * t + 3, a.w + bq.w + c.w + d.w);
        }
    } else {
        // gene projection k-chunk of 256
        int k0 = (blk - 1024) * 256;
        for (int b = 0; b < BB; b++) {
            float x = F_gene[(size_t)b * GIN + k0 + t];
            float m = ws[WS_GMEAN + b], r = ws[WS_GRSTD + b];
            lds[b * 256 + t] = (x - m) * r * gene_ln_g[k0 + t] + gene_ln_b[k0 + t];
        }
        __syncthreads();
        float acc0[BB], acc1[BB];
#pragma unroll
        for (int b = 0; b < BB; b++) { acc0[b] = 0.f; acc1[b] = 0.f; }
        int d0 = t, d1 = t + 256;
#pragma unroll 8
        for (int kk = 0; kk < 256; kk++) {
            float w0 = gene_W[(size_t)(k0 + kk) * DIM + d0];
            float w1 = gene_W[(size_t)(k0 + kk) * DIM + d1];
#pragma unroll
            for (int b = 0; b < BB; b++) {
                float y = lds[b * 256 + kk];
                acc0[b] += y * w0; acc1[b] += y * w1;
            }
        }
        for (int b = 0; b < BB; b++) {
            atomicAdd(ws + WS_XG + b * DIM + d0, acc0[b]);
            atomicAdd(ws + WS_XG + b * DIM + d1, acc1[b]);
        }
    }
}

// ============ skinny GEMM: out[M,512] += A[M,1024] @ W[1024,512], k-split ============
// pool=1: A rows from Z/SUMXN with path affine (M=80, grid 80); pool=0: A = tl (M=16, grid 16)
__global__ __launch_bounds__(256) void k_skinny(const float* __restrict__ A,
                                                const float* __restrict__ W,
                                                float* __restrict__ out,
                                                const float* __restrict__ lng,
                                                const float* __restrict__ lnb,
                                                const float* __restrict__ ws,
                                                int pool) {
    __shared__ __align__(16) float a[16 * 64];
    int blk = blockIdx.x, t = threadIdx.x;
    int rg = blk >> 4, kc = blk & 15;
    for (int i = t; i < 1024; i += 256) {
        int r = rg * 16 + (i >> 6);
        int k = kc * 64 + (i & 63);
        float v;
        if (pool) {
            v = (r < 64) ? ws[WS_Z + (size_t)r * PIN + k]
                         : ws[WS_SUMXN + (size_t)(r - 64) * PIN + k] * (1.f / NTOK);
            v = v * lng[k] + lnb[k];
        } else {
            v = A[(size_t)r * PIN + k];
        }
        a[i] = v;
    }
    __syncthreads();
    float2 acc[16];
#pragma unroll
    for (int r = 0; r < 16; r++) acc[r] = make_float2(0.f, 0.f);
    int d2 = 2 * t;
#pragma unroll 4
    for (int k = 0; k < 64; k++) {
        float2 wv = *(const float2*)&W[(size_t)(kc * 64 + k) * DIM + d2];
#pragma unroll
        for (int r = 0; r < 16; r++) {
            float av = a[r * 64 + k];
            acc[r].x += av * wv.x;
            acc[r].y += av * wv.y;
        }
    }
#pragma unroll
    for (int r = 0; r < 16; r++) {
        int rr = rg * 16 + r;
        atomicAdd(out + (size_t)rr * DIM + d2 + 0, acc[r].x);
        atomicAdd(out + (size_t)rr * DIM + d2 + 1, acc[r].y);
    }
}

// ============ K5: row LN + gating + expert-input affine ============
__global__ __launch_bounds__(256) void k5_rows(const float* __restrict__ gene_b,
    const float* __restrict__ path_b,
    const float* __restrict__ gg_ln_g, const float* __restrict__ gg_ln_b,
    const float* __restrict__ gg_W, const float* __restrict__ gg_b,
    const float* __restrict__ pg_ln_g, const float* __restrict__ pg_ln_b,
    const float* __restrict__ pg_W, const float* __restrict__ pg_b,
    const float* __restrict__ g_ln_g, const float* __restrict__ g_ln_b,
    const float* __restrict__ p_ln_g, const float* __restrict__ p_ln_b,
    float* __restrict__ ws) {
    int blk = blockIdx.x, t = threadIdx.x;
    __shared__ float sc[8];
    __shared__ float sc2[16];
    int c0 = t, c1 = t + 256;
    int w = t >> 6, lane = t & 63;
    float v0, v1;
    int type, b = 0, r = 0;
    if (blk < 16) {
        type = 0; b = blk;
        v0 = ws[WS_XG + b * DIM + c0] + gene_b[c0];
        v1 = ws[WS_XG + b * DIM + c1] + gene_b[c1];
    } else if (blk < 32) {
        type = 1; b = blk - 16;
        v0 = ws[WS_XPMEAN + b * DIM + c0] + path_b[c0];
        v1 = ws[WS_XPMEAN + b * DIM + c1] + path_b[c1];
    } else {
        type = 2; r = blk - 32;
        v0 = ws[WS_POOLED + r * DIM + c0] + path_b[c0];
        v1 = ws[WS_POOLED + r * DIM + c1] + path_b[c1];
    }
    float s1 = wsum(v0 + v1), s2 = wsum(v0 * v0 + v1 * v1);
    if (lane == 0) { sc[w] = s1; sc[4 + w] = s2; }
    __syncthreads();
    s1 = sc[0] + sc[1] + sc[2] + sc[3];
    s2 = sc[4] + sc[5] + sc[6] + sc[7];
    float m = s1 / DIM, var = s2 / DIM - m * m, rs = rsqrtf(var + EPS);
    float xn0 = (v0 - m) * rs, xn1 = (v1 - m) * rs;
    if (type == 0) {
#pragma unroll
        for (int e = 0; e < NGE; e++) {
            ws[WS_UG + (e * BB + b) * DIM + c0] = xn0 * g_ln_g[e * DIM + c0] + g_ln_b[e * DIM + c0];
            ws[WS_UG + (e * BB + b) * DIM + c1] = xn1 * g_ln_g[e * DIM + c1] + g_ln_b[e * DIM + c1];
        }
        float t0 = xn0 * gg_ln_g[c0] + gg_ln_b[c0];
        float t1 = xn1 * gg_ln_g[c1] + gg_ln_b[c1];
        float l[4];
#pragma unroll
        for (int e = 0; e < 4; e++) l[e] = wsum(t0 * gg_W[c0 * 4 + e] + t1 * gg_W[c1 * 4 + e]);
        if (lane == 0)
#pragma unroll
            for (int e = 0; e < 4; e++) sc2[w * 4 + e] = l[e];
        __syncthreads();
        if (t == 0) {
            float lg[4], mx = -1e30f;
#pragma unroll
            for (int e = 0; e < 4; e++) {
                lg[e] = sc2[e] + sc2[4 + e] + sc2[8 + e] + sc2[12 + e] + gg_b[e];
                mx = fmaxf(mx, lg[e]);
            }
            float sum = 0.f;
#pragma unroll
            for (int e = 0; e < 4; e++) { lg[e] = __expf(lg[e] - mx); sum += lg[e]; }
#pragma unroll
            for (int e = 0; e < 4; e++) ws[WS_WG + b * NGE + e] = lg[e] / sum;
        }
    } else if (type == 1) {
        float t0 = xn0 * pg_ln_g[c0] + pg_ln_b[c0];
        float t1 = xn1 * pg_ln_g[c1] + pg_ln_b[c1];
        float l[4];
#pragma unroll
        for (int e = 0; e < 4; e++) l[e] = wsum(t0 * pg_W[c0 * 4 + e] + t1 * pg_W[c1 * 4 + e]);
        if (lane == 0)
#pragma unroll
            for (int e = 0; e < 4; e++) sc2[w * 4 + e] = l[e];
        __syncthreads();
        if (t == 0) {
            float lg[4], mx = -1e30f;
#pragma unroll
            for (int e = 0; e < 4; e++) {
                lg[e] = sc2[e] + sc2[4 + e] + sc2[8 + e] + sc2[12 + e] + pg_b[e];
                mx = fmaxf(mx, lg[e]);
            }
            float sum = 0.f;
#pragma unroll
            for (int e = 0; e < 4; e++) { lg[e] = __expf(lg[e] - mx); sum += lg[e]; }
#pragma unroll
            for (int e = 0; e < 4; e++) ws[WS_WP + b * NPE + e] = lg[e] / sum;
        }
    } else {
        int e = r >> 4;
        ws[WS_UP + r * DIM + c0] = xn0 * p_ln_g[e * DIM + c0] + p_ln_b[e * DIM + c0];
        ws[WS_UP + r * DIM + c1] = xn1 * p_ln_g[e * DIM + c1] + p_ln_b[e * DIM + c1];
    }
}

// ============ MLP layer1 pre-act: Hacc[e,b,h] += sum_k U[e,b,k] W1[e,k,h] ============
// per set: e x ht(4, 512h) x kc(8, 64k). thread owns 2 h (float2).
__global__ __launch_bounds__(256) void k_mlp1(const float* __restrict__ U0, const float* __restrict__ W10,
                                              float* __restrict__ H0,
                                              const float* __restrict__ U1, const float* __restrict__ W11,
                                              float* __restrict__ H1,
                                              int halfBlk) {
    __shared__ float a[16 * 64];
    int blk = blockIdx.x, t = threadIdx.x;
    const float* U; const float* W1; float* H;
    int lb;
    if (blk < halfBlk) { U = U0; W1 = W10; H = H0; lb = blk; }
    else               { U = U1; W1 = W11; H = H1; lb = blk - halfBlk; }
    int e = lb >> 5, ht = (lb >> 3) & 3, kc = lb & 7;
    const float* Ue = U + (size_t)e * BB * DIM;
    for (int i = t; i < 1024; i += 256) {
        int b = i >> 6, kk = i & 63;
        a[i] = Ue[b * DIM + kc * 64 + kk];
    }
    __syncthreads();
    float2 acc[BB];
#pragma unroll
    for (int b = 0; b < BB; b++) acc[b] = make_float2(0.f, 0.f);
    int h2 = ht * 512 + 2 * t;
#pragma unroll 4
    for (int kk = 0; kk < 64; kk++) {
        float2 wv = *(const float2*)&W1[((size_t)e * DIM + kc * 64 + kk) * HID + h2];
#pragma unroll
        for (int b = 0; b < BB; b++) {
            float av = a[b * 64 + kk];
            acc[b].x += av * wv.x;
            acc[b].y += av * wv.y;
        }
    }
#pragma unroll
    for (int b = 0; b < BB; b++) {
        atomicAdd(H + (size_t)(e * BB + b) * HID + h2 + 0, acc[b].x);
        atomicAdd(H + (size_t)(e * BB + b) * HID + h2 + 1, acc[b].y);
    }
}

// ============ GELU+bias in place: H = gelu(H + b1) ============
__global__ __launch_bounds__(256) void k_gelu(float* __restrict__ H,
                                              const float* __restrict__ b1a,
                                              const float* __restrict__ b1b,
                                              int eSplit) {
    int idx4 = (blockIdx.x * 256 + threadIdx.x) * 4;
    int e = idx4 >> 15;           // per-e block is 16*2048 = 32768
    int h = idx4 & (HID - 1);
    const float* bp = (e < eSplit) ? (b1a + (size_t)e * HID) : (b1b + (size_t)(e - eSplit) * HID);
    float4 v = *(float4*)&H[idx4];
    float4 bv = *(const float4*)&bp[h];
    v.x = gelu_exact(v.x + bv.x);
    v.y = gelu_exact(v.y + bv.y);
    v.z = gelu_exact(v.z + bv.z);
    v.w = gelu_exact(v.w + bv.w);
    *(float4*)&H[idx4] = v;
}

// ============ MLP layer2 + gate-weighted accumulate (bias b2 folded downstream) ============
// per set: e x kc(16, 128k). thread owns 2 d (float2).
__global__ __launch_bounds__(256) void k_mlp2(const float* __restrict__ H0, const float* __restrict__ W20,
                                              const float* __restrict__ gate0, int ng0, float* __restrict__ out0,
                                              const float* __restrict__ H1, const float* __restrict__ W21,
                                              const float* __restrict__ gate1, int ng1, float* __restrict__ out1,
                                              int halfBlk) {
    __shared__ float a[16 * 128];
    int blk = blockIdx.x, t = threadIdx.x;
    const float* H; const float* W2; const float* gate; float* outp;
    int ng, lb;
    if (blk < halfBlk) { H = H0; W2 = W20; gate = gate0; ng = ng0; outp = out0; lb = blk; }
    else               { H = H1; W2 = W21; gate = gate1; ng = ng1; outp = out1; lb = blk - halfBlk; }
    int e = lb >> 4, kc = lb & 15;
    for (int i = t; i < 2048; i += 256) {
        int b = i >> 7, kk = i & 127;
        a[i] = H[(size_t)(e * BB + b) * HID + kc * 128 + kk];
    }
    __syncthreads();
    float2 acc[BB];
#pragma unroll
    for (int b = 0; b < BB; b++) acc[b] = make_float2(0.f, 0.f);
    int d2 = 2 * t;
#pragma unroll 4
    for (int kk = 0; kk < 128; kk++) {
        float2 wv = *(const float2*)&W2[((size_t)e * HID + kc * 128 + kk) * DIM + d2];
#pragma unroll
        for (int b = 0; b < BB; b++) {
            float av = a[b * 128 + kk];
            acc[b].x += av * wv.x;
            acc[b].y += av * wv.y;
        }
    }
#pragma unroll
    for (int b = 0; b < BB; b++) {
        float g = gate[b * ng + e];
        atomicAdd(outp + (size_t)b * DIM + d2 + 0, g * acc[b].x);
        atomicAdd(outp + (size_t)b * DIM + d2 + 1, g * acc[b].y);
    }
}

// ============ K8a: fused = [FG+bias | FP+bias]; LN; wf gates; tl = affine(fin_ln) ============
__global__ __launch_bounds__(256) void k8a(const float* __restrict__ fg_ln_g, const float* __restrict__ fg_ln_b,
                                           const float* __restrict__ fg_W, const float* __restrict__ fg_b,
                                           const float* __restrict__ fin_ln_g, const float* __restrict__ fin_ln_b,
                                           const float* __restrict__ g_b2, const float* __restrict__ p_b2,
                                           float* __restrict__ ws) {
    __shared__ float sc[8];
    __shared__ float sc2[8];
    int b = blockIdx.x, t = threadIdx.x;
    int w = t >> 6, lane = t & 63;
    float wg[4], wp[4];
#pragma unroll
    for (int e = 0; e < 4; e++) { wg[e] = ws[WS_WG + b * 4 + e]; wp[e] = ws[WS_WP + b * 4 + e]; }
    float v[4];
    v[0] = ws[WS_FG + b * DIM + t]
         + wg[0] * g_b2[t] + wg[1] * g_b2[DIM + t] + wg[2] * g_b2[2 * DIM + t] + wg[3] * g_b2[3 * DIM + t];
    v[1] = ws[WS_FG + b * DIM + t + 256]
         + wg[0] * g_b2[t + 256] + wg[1] * g_b2[DIM + t + 256] + wg[2] * g_b2[2 * DIM + t + 256] + wg[3] * g_b2[3 * DIM + t + 256];
    v[2] = ws[WS_FP + b * DIM + t]
         + wp[0] * p_b2[t] + wp[1] * p_b2[DIM + t] + wp[2] * p_b2[2 * DIM + t] + wp[3] * p_b2[3 * DIM + t];
    v[3] = ws[WS_FP + b * DIM + t + 256]
         + wp[0] * p_b2[t + 256] + wp[1] * p_b2[DIM + t + 256] + wp[2] * p_b2[2 * DIM + t + 256] + wp[3] * p_b2[3 * DIM + t + 256];
    float s1 = wsum(v[0] + v[1] + v[2] + v[3]);
    float s2 = wsum(v[0] * v[0] + v[1] * v[1] + v[2] * v[2] + v[3] * v[3]);
    if (lane == 0) { sc[w] = s1; sc[4 + w] = s2; }
    __syncthreads();
    s1 = sc[0] + sc[1] + sc[2] + sc[3];
    s2 = sc[4] + sc[5] + sc[6] + sc[7];
    float m = s1 / (2 * DIM), var = s2 / (2 * DIM) - m * m, rs = rsqrtf(var + EPS);
    float l0 = 0.f, l1 = 0.f;
    int cols[4] = {t, t + 256, t + 512, t + 768};
#pragma unroll
    for (int j = 0; j < 4; j++) {
        int c = cols[j];
        float xn = (v[j] - m) * rs;
        float tf = xn * fg_ln_g[c] + fg_ln_b[c];
        l0 += tf * fg_W[c * 2 + 0];
        l1 += tf * fg_W[c * 2 + 1];
        ws[WS_TL + b * 1024 + c] = xn * fin_ln_g[c] + fin_ln_b[c];
    }
    l0 = wsum(l0); l1 = wsum(l1);
    if (lane == 0) { sc2[w] = l0; sc2[4 + w] = l1; }
    __syncthreads();
    if (t == 0) {
        float L0 = sc2[0] + sc2[1] + sc2[2] + sc2[3] + fg_b[0];
        float L1 = sc2[4] + sc2[5] + sc2[6] + sc2[7] + fg_b[1];
        float mx = fmaxf(L0, L1);
        float p0 = __expf(L0 - mx), p1 = __expf(L1 - mx);
        float inv = 1.f / (p0 + p1);
        ws[WS_WF + b * NFE + 0] = p0 * inv;
        ws[WS_WF + b * NFE + 1] = p1 * inv;
    }
}

// ============ K8b: LN(FIN + fin_b) -> UF (f-expert affine) ============
__global__ __launch_bounds__(256) void k8b(const float* __restrict__ fin_b,
                                           const float* __restrict__ f_ln_g, const float* __restrict__ f_ln_b,
                                           float* __restrict__ ws) {
    __shared__ float sc[8];
    int b = blockIdx.x, t = threadIdx.x;
    int w = t >> 6, lane = t & 63;
    int c0 = t, c1 = t + 256;
    float a0 = ws[WS_FIN + b * DIM + c0] + fin_b[c0];
    float a1 = ws[WS_FIN + b * DIM + c1] + fin_b[c1];
    float s1 = wsum(a0 + a1), s2 = wsum(a0 * a0 + a1 * a1);
    if (lane == 0) { sc[w] = s1; sc[4 + w] = s2; }
    __syncthreads();
    s1 = sc[0] + sc[1] + sc[2] + sc[3];
    s2 = sc[4] + sc[5] + sc[6] + sc[7];
    float m = s1 / DIM, var = s2 / DIM - m * m, rs = rsqrtf(var + EPS);
    float x0 = (a0 - m) * rs, x1 = (a1 - m) * rs;
#pragma unroll
    for (int e = 0; e < NFE; e++) {
        ws[WS_UF + (e * BB + b) * DIM + c0] = x0 * f_ln_g[e * DIM + c0] + f_ln_b[e * DIM + c0];
        ws[WS_UF + (e * BB + b) * DIM + c1] = x1 * f_ln_g[e * DIM + c1] + f_ln_b[e * DIM + c1];
    }
}

// ============ K11: classifier (+gate-weighted f_b2 bias) + sigmoid + cumprod ============
__global__ __launch_bounds__(256) void k11_out(const float* __restrict__ cls_W, const float* __restrict__ cls_b,
                                               const float* __restrict__ f_b2,
                                               const float* __restrict__ ws, float* __restrict__ out) {
    __shared__ float4 red[256];
    __shared__ float hz[64];
    int t = threadIdx.x;
    int b = t >> 4, g = t & 15;
    float wf0 = ws[WS_WF + b * 2 + 0], wf1 = ws[WS_WF + b * 2 + 1];
    float4 acc = make_float4(0.f, 0.f, 0.f, 0.f);
#pragma unroll 8
    for (int k = g; k < DIM; k += 16) {
        float x = ws[WS_FIMMF + b * DIM + k] + wf0 * f_b2[k] + wf1 * f_b2[DIM + k];
        float4 wv = *(const float4*)&cls_W[k * 4];
        acc.x += x * wv.x; acc.y += x * wv.y; acc.z += x * wv.z; acc.w += x * wv.w;
    }
    red[t] = acc;
    __syncthreads();
    if (t < 64) {
        int bb = t >> 2, c = t & 3;
        float s = cls_b[c];
#pragma unroll
        for (int j = 0; j < 16; j++) s += ((const float*)&red[bb * 16 + j])[c];
        hz[t] = 1.f / (1.f + __expf(-s));
    }
    __syncthreads();
    if (t < 64) {
        int bb = t >> 2, c = t & 3;
        float S = 1.f;
        for (int j = 0; j <= c; j++) S *= (1.f - hz[bb * 4 + j]);
        out[t] = hz[t];
        out[64 + t] = S;
    }
}

extern "C" void kernel_launch(void* const* d_in, const int* in_sizes, int n_in,
                              void* d_out, int out_size, void* d_ws, size_t ws_size,
                              hipStream_t stream) {
    (void)in_sizes; (void)n_in; (void)out_size; (void)ws_size;
    const float* F_gene    = (const float*)d_in[0];
    const float* F_path    = (const float*)d_in[1];
    const float* gene_ln_g = (const float*)d_in[2];
    const float* gene_ln_b = (const float*)d_in[3];
    const float* gene_W    = (const float*)d_in[4];
    const float* gene_b    = (const float*)d_in[5];
    const float* path_ln_g = (const float*)d_in[6];
    const float* path_ln_b = (const float*)d_in[7];
    const float* path_W    = (const float*)d_in[8];
    const float* path_b    = (const float*)d_in[9];
    const float* g_ln_g    = (const float*)d_in[10];
    const float* g_ln_b    = (const float*)d_in[11];
    const float* g_W1      = (const float*)d_in[12];
    const float* g_b1      = (const float*)d_in[13];
    const float* g_W2      = (const float*)d_in[14];
    const float* g_b2      = (const float*)d_in[15];
    const float* p_q       = (const float*)d_in[16];
    const float* p_ln_g    = (const float*)d_in[17];
    const float* p_ln_b    = (const float*)d_in[18];
    const float* p_W1      = (const float*)d_in[19];
    const float* p_b1      = (const float*)d_in[20];
    const float* p_W2      = (const float*)d_in[21];
    const float* p_b2      = (const float*)d_in[22];
    const float* f_ln_g    = (const float*)d_in[23];
    const float* f_ln_b    = (const float*)d_in[24];
    const float* f_W1      = (const float*)d_in[25];
    const float* f_b1      = (const float*)d_in[26];
    const float* f_W2      = (const float*)d_in[27];
    const float* f_b2      = (const float*)d_in[28];
    const float* gg_ln_g   = (const float*)d_in[29];
    const float* gg_ln_b   = (const float*)d_in[30];
    const float* gg_W      = (const float*)d_in[31];
    const float* gg_b      = (const float*)d_in[32];
    const float* pg_ln_g   = (const float*)d_in[33];
    const float* pg_ln_b   = (const float*)d_in[34];
    const float* pg_W      = (const float*)d_in[35];
    const float* pg_b      = (const float*)d_in[36];
    const float* fg_ln_g   = (const float*)d_in[37];
    const float* fg_ln_b   = (const float*)d_in[38];
    const float* fg_W      = (const float*)d_in[39];
    const float* fg_b      = (const float*)d_in[40];
    const float* fin_ln_g  = (const float*)d_in[41];
    const float* fin_ln_b  = (const float*)d_in[42];
    const float* fin_W     = (const float*)d_in[43];
    const float* fin_b     = (const float*)d_in[44];
    const float* cls_W     = (const float*)d_in[45];
    const float* cls_b     = (const float*)d_in[46];
    float* ws  = (float*)d_ws;
    float* out = (float*)d_out;

    k0_init<<<512, 256, 0, stream>>>(F_gene, path_W, p_q, path_ln_g, ws);
    k1_pass1<<<1024, 256, 0, stream>>>(F_path, ws);
    k2_softmax<<<64, 256, 0, stream>>>(ws);
    k3_pass2<<<1040, 256, 0, stream>>>(F_path, F_gene, gene_W, gene_ln_g, gene_ln_b, ws);
    k_skinny<<<80, 256, 0, stream>>>(nullptr, path_W, ws + WS_POOLED, path_ln_g, path_ln_b, ws, 1);
    k5_rows<<<96, 256, 0, stream>>>(gene_b, path_b, gg_ln_g, gg_ln_b, gg_W, gg_b,
                                    pg_ln_g, pg_ln_b, pg_W, pg_b,
                                    g_ln_g, g_ln_b, p_ln_g, p_ln_b, ws);
    k_mlp1<<<256, 256, 0, stream>>>(ws + WS_UG, g_W1, ws + WS_HG,
                                    ws + WS_UP, p_W1, ws + WS_HP, 128);
    k_gelu<<<256, 256, 0, stream>>>(ws + WS_HG, g_b1, p_b1, 4);
    k_mlp2<<<128, 256, 0, stream>>>(ws + WS_HG, g_W2, ws + WS_WG, NGE, ws + WS_FG,
                                    ws + WS_HP, p_W2, ws + WS_WP, NPE, ws + WS_FP, 64);
    k8a<<<16, 256, 0, stream>>>(fg_ln_g, fg_ln_b, fg_W, fg_b, fin_ln_g, fin_ln_b, g_b2, p_b2, ws);
    k_skinny<<<16, 256, 0, stream>>>(ws + WS_TL, fin_W, ws + WS_FIN, nullptr, nullptr, ws, 0);
    k8b<<<16, 256, 0, stream>>>(fin_b, f_ln_g, f_ln_b, ws);
    k_mlp1<<<64, 256, 0, stream>>>(ws + WS_UF, f_W1, ws + WS_HF,
                                   ws + WS_UF, f_W1, ws + WS_HF, 64);
    k_gelu<<<64, 256, 0, stream>>>(ws + WS_HF, f_b1, f_b1, 2);
    k_mlp2<<<32, 256, 0, stream>>>(ws + WS_HF, f_W2, ws + WS_WF, NFE, ws + WS_FIMMF,
                                   ws + WS_HF, f_W2, ws + WS_WF, NFE, ws + WS_FIMMF, 32);
    k11_out<<<1, 256, 0, stream>>>(cls_W, cls_b, f_b2, ws, out);
}